// Round 7
// baseline (1064.296 us; speedup 1.0000x reference)
//
#include <hip/hip_runtime.h>
#include <math.h>

#define V 23
#define HH 256
#define BB 512
#define LL 1024
#define NOUT 46  // 2V

typedef float f32x2 __attribute__((ext_vector_type(2)));
typedef float f32x4 __attribute__((ext_vector_type(4)));

// Multiplicative inverses mod 23, packed 5 bits/entry into two u64 scalars
// (entries 0..11 in T0, 12..22 in T1) so the inverse lookup is pure SALU.
constexpr unsigned long long packInv(int lo) {
    const int inv[23] = {0,1,12,8,6,14,4,10,3,18,7,21,2,16,5,20,13,19,9,17,15,11,22};
    unsigned long long t = 0;
    for (int i = 0; i < 12; ++i) {
        int idx = lo + i;
        if (idx < 23) t |= (unsigned long long)inv[idx] << (5 * i);
    }
    return t;
}
constexpr unsigned long long INV_T0 = packInv(0);
constexpr unsigned long long INV_T1 = packInv(12);

// VALU max-reduce step via DPP (no DS pipe, ~8 cy vs ~120 cy ds_swizzle)
#define DPPMAX(v, ctrl, rmask)                                                  \
    do {                                                                        \
        unsigned _t = (unsigned)__builtin_amdgcn_update_dpp(                    \
            (int)(v), (int)(v), (ctrl), (rmask), 0xF, false);                   \
        (v) = ((v) > _t) ? (v) : _t;                                            \
    } while (0)

// Argmax tail (identical to R7): net -> emitted symbol k. Uses DPP-only
// dual-half max reduce + ballot tie-break (lowest lane = np first-max).
__device__ __forceinline__ int pick_k(float net, bool active, int l, int tok) {
    int ib = __float_as_int(net);
    unsigned monoraw = (ib < 0) ? ~(unsigned)ib : ((unsigned)ib ^ 0x80000000u);
    const unsigned orig = active ? monoraw : 0u;  // lane's OWN key, preserved
    unsigned red = orig;
    DPPMAX(red, 0xB1,  0xF);  // quad_perm xor1
    DPPMAX(red, 0x4E,  0xF);  // quad_perm xor2
    DPPMAX(red, 0x141, 0xF);  // row_half_mirror (combine 4-groups)
    DPPMAX(red, 0x140, 0xF);  // row_mirror      (combine 8-groups)
    DPPMAX(red, 0x142, 0xA);  // row_bcast15 into rows 1,3 (combine rows)
    const unsigned sA = (unsigned)__builtin_amdgcn_readlane((int)red, 16);
    const unsigned sB = (unsigned)__builtin_amdgcn_readlane((int)red, 48);
    const unsigned cmpv = (l < 32) ? sA : sB;
    const unsigned long long bal = __ballot(orig == cmpv);
    const int loc = __builtin_ctzll(bal & 0xFFFFFFFFull);  // lane == col
    const int sc  = __builtin_ctzll(bal >> 32);
    // inverse mod 23 from packed scalar table (no LDS on the chain)
    const unsigned long long tt = (sc < 12) ? INV_T0 : INV_T1;
    const int sh  = 5 * (sc - ((sc >= 12) ? 12 : 0));
    const int inv = (int)((tt >> sh) & 31);
    int m = tok - loc;
    m += (m >> 31) & V;            // (tok - loc) mod 23
    return (m * inv) % V;          // compiler magic-mul for %23
}

// R10: revert R9's tree (VALU-chain work lost twice: +68us R5, +76us R9 —
// co-resident waves hide DS LATENCY but not VALU ISSUE) and attack the real
// binder: 56% of issue slots idle from phase-correlated stalls of the two
// co-resident blocks. Fuse TWO sequences into one block (grid 512->256):
// W2 regs are SHARED (same lane->col map), only h/acc/tok state duplicates.
// The two sequences' matvecs, DPP chains, and sW1 reads are independent and
// interleave at INSTRUCTION granularity; one barrier covers both partials.
// Per-sequence arithmetic is instruction-identical to R7 -> bit-exact.
__global__ __launch_bounds__(256, 1)
void daf_kernel(const int* __restrict__ xtok,
                const float* __restrict__ W1,
                const float* __restrict__ b1,
                const float* __restrict__ W2,
                const float* __restrict__ b2,
                float* __restrict__ out)
{
    __shared__ float sW1[V * HH];     // W1 rows for the h-update (shared by both seqs)
    __shared__ float sV[2][HH];       // relu(h) per seq; wave w touches [64w,64w+64)
    __shared__ float sP[2][2][4][64]; // partials [parity][seq][wave][lane]
    __shared__ int   sTok[2][LL];
    __shared__ int   sK[2][LL];       // emitted symbols; flushed at end

    const int tid = threadIdx.x;
    const int w   = tid >> 6;
    const int l   = tid & 63;
    const int b   = blockIdx.x;       // handles sequences 2b and 2b+1

    for (int i = tid; i < V * HH; i += 256) sW1[i] = W1[i];
    for (int i = tid; i < LL; i += 256) {
        sTok[0][i] = xtok[(size_t)(2 * b + 0) * LL + i];
        sTok[1][i] = xtok[(size_t)(2 * b + 1) * LL + i];
    }

    // Lane roles: lanes 0..22 own net[:V] (loc), lanes 32..54 own net[V:] (scale).
    const bool activeA = (l < V);
    const bool activeB = (l >= 32 && l < 32 + V);
    const bool active  = activeA || activeB;
    const int  col     = activeA ? l : (activeB ? (l - 32 + V) : 0);

    // h state per sequence, in double: 1024 sequential adds stay within 1 ulp.
    double hA = (double)b1[tid];
    double hB = (double)b1[tid];

    const float bias = active ? b2[col] : 0.f;

    // W2 chunk as 32 float2 pairs (SHARED across both sequences): lane holds
    // W2[64w+ii][col], PINNED in VGPR pairs for v_pk_fma_f32 (R7: -77us).
    f32x2 wreg2[32];
    #pragma unroll
    for (int ii = 0; ii < 32; ++ii) {
        wreg2[ii].x = active ? W2[(size_t)(64 * w + 2 * ii + 0) * NOUT + col] : 0.f;
        wreg2[ii].y = active ? W2[(size_t)(64 * w + 2 * ii + 1) * NOUT + col] : 0.f;
    }
    #pragma unroll
    for (int ii = 0; ii < 32; ++ii) asm volatile("" : "+v"(wreg2[ii]));

    __syncthreads();

    for (int t = 0; t < LL; ++t) {
        const int tokA = sTok[0][t];   // issued early; latency under matvec
        const int tokB = sTok[1][t];

        // publish relu(h) for both seqs; each wave reads only its OWN window
        // it wrote itself (wave-internal; lgkmcnt orders it, no barrier).
        sV[0][tid] = fmaxf((float)hA, 0.f);
        sV[1][tid] = fmaxf((float)hB, 0.f);

        // two independent matvec partials; uniform-address b128 reads
        // broadcast; per-seq accumulation order IDENTICAL to R7.
        const f32x4* pvA = (const f32x4*)(sV[0] + 64 * w);
        const f32x4* pvB = (const f32x4*)(sV[1] + 64 * w);
        f32x2 A01 = {0.f, 0.f}, A23 = {0.f, 0.f};
        f32x2 B01 = {0.f, 0.f}, B23 = {0.f, 0.f};
        #pragma unroll
        for (int q = 0; q < 16; ++q) {
            f32x4 va = pvA[q];
            f32x4 vb = pvB[q];
            f32x2 valo = __builtin_shufflevector(va, va, 0, 1);
            f32x2 vahi = __builtin_shufflevector(va, va, 2, 3);
            f32x2 vblo = __builtin_shufflevector(vb, vb, 0, 1);
            f32x2 vbhi = __builtin_shufflevector(vb, vb, 2, 3);
            asm("v_pk_fma_f32 %0, %1, %2, %0" : "+v"(A01) : "v"(valo), "v"(wreg2[2 * q + 0]));
            asm("v_pk_fma_f32 %0, %1, %2, %0" : "+v"(A23) : "v"(vahi), "v"(wreg2[2 * q + 1]));
            asm("v_pk_fma_f32 %0, %1, %2, %0" : "+v"(B01) : "v"(vblo), "v"(wreg2[2 * q + 0]));
            asm("v_pk_fma_f32 %0, %1, %2, %0" : "+v"(B23) : "v"(vbhi), "v"(wreg2[2 * q + 1]));
        }
        const int p = t & 1;
        sP[p][0][w][l] = (A01.x + A01.y) + (A23.x + A23.y);
        sP[p][1][w][l] = (B01.x + B01.y) + (B23.x + B23.y);
        __syncthreads();   // ONE barrier per step, covers both sequences

        // reduce 4 wave-partials + bias per seq; order (s0+s1)+(s2+s3) kept.
        // (locals named qa*/qb* — R6 compile error was b2v/b1v shadowing the
        // b1/b2 POINTER parameters)
        const float* ppA = &sP[p][0][0][l];
        const float* ppB = &sP[p][1][0][l];
        const float qa0 = ppA[0], qa1 = ppA[64], qa2 = ppA[128], qa3 = ppA[192];
        const float qb0 = ppB[0], qb1 = ppB[64], qb2 = ppB[128], qb3 = ppB[192];
        const float netA = bias + ((qa0 + qa1) + (qa2 + qa3));
        const float netB = bias + ((qb0 + qb1) + (qb2 + qb3));

        // two independent argmax tails — interleave in each other's shadow
        const int kA = pick_k(netA, active, l, tokA);
        const int kB = pick_k(netB, active, l, tokB);

        // h updates: stride-1 conflict-free LDS reads (idle DS pipe)
        hA += (double)sW1[kA * HH + tid];
        hB += (double)sW1[kB * HH + tid];
        if (tid == 0) { sK[0][t] = kA; sK[1][t] = kB; }
    }

    __syncthreads();
    for (int s = 0; s < 2; ++s) {
        float* outb = out + (size_t)(2 * b + s) * LL * V;
        for (int t = tid; t < LL; t += 256)
            outb[t * V + sK[s][t]] = 1.0f;
    }
}

extern "C" void kernel_launch(void* const* d_in, const int* in_sizes, int n_in,
                              void* d_out, int out_size, void* d_ws, size_t ws_size,
                              hipStream_t stream) {
    const int*   xtok = (const int*)d_in[0];
    const float* W1   = (const float*)d_in[1];
    const float* b1   = (const float*)d_in[2];
    const float* W2   = (const float*)d_in[3];
    const float* b2   = (const float*)d_in[4];
    float* out = (float*)d_out;

    // d_out poisoned 0xAA pre-launch: zero it, kernel scatters the 1.0s
    hipMemsetAsync(out, 0, (size_t)out_size * sizeof(float), stream);
    daf_kernel<<<BB / 2, 256, 0, stream>>>(xtok, W1, b1, W2, b2, out);
}

// Round 8
// 695.493 us; speedup vs baseline: 1.5303x; 1.5303x over previous
//
#include <hip/hip_runtime.h>
#include <math.h>

#define V 23
#define HH 256
#define BB 512
#define LL 1024
#define NOUT 46  // 2V

typedef float f32x2 __attribute__((ext_vector_type(2)));
typedef float f32x4 __attribute__((ext_vector_type(4)));

// Multiplicative inverses mod 23, packed 5 bits/entry into two u64 scalars
// (entries 0..11 in T0, 12..22 in T1) so the inverse lookup is pure SALU.
constexpr unsigned long long packInv(int lo) {
    const int inv[23] = {0,1,12,8,6,14,4,10,3,18,7,21,2,16,5,20,13,19,9,17,15,11,22};
    unsigned long long t = 0;
    for (int i = 0; i < 12; ++i) {
        int idx = lo + i;
        if (idx < 23) t |= (unsigned long long)inv[idx] << (5 * i);
    }
    return t;
}
constexpr unsigned long long INV_T0 = packInv(0);
constexpr unsigned long long INV_T1 = packInv(12);

// VALU max-reduce step via DPP (no DS pipe, ~8 cy vs ~120 cy ds_swizzle)
#define DPPMAX(v, ctrl, rmask)                                                  \
    do {                                                                        \
        unsigned _t = (unsigned)__builtin_amdgcn_update_dpp(                    \
            (int)(v), (int)(v), (ctrl), (rmask), 0xF, false);                   \
        (v) = ((v) > _t) ? (v) : _t;                                            \
    } while (0)

// R11: R7 structure EXACTLY (674us best: 4 waves, 2 blocks/CU, pk_fma matvec,
// LDS sV broadcast, sP[2][4][64], one barrier). R10's fusion refuted ILP
// (1044us): the co-resident blocks already overlap; the binder is R7's
// per-step chain latency C~1580cy, of which ~700cy is unexplained by the
// component sum (~900). Theory: the OTHER block's issue-elastic matvec
// bursts delay our chain-critical ops at every arbitration point. Fix = T5
// setprio: the serial chain (post-barrier reduce -> DPP argmax -> k -> sW1
// -> h += -> relu -> next sV write) runs at prio 1; the matvec at prio 0.
// First sV write peeled so the whole chain lives in one prio-1 region.
__global__ __launch_bounds__(256, 2)
void daf_kernel(const int* __restrict__ xtok,
                const float* __restrict__ W1,
                const float* __restrict__ b1,
                const float* __restrict__ W2,
                const float* __restrict__ b2,
                float* __restrict__ out)
{
    __shared__ float sW1[V * HH];     // W1 rows for the h-update
    __shared__ float sV[HH];          // relu(h); wave w only touches [64w,64w+64)
    __shared__ float sP[2][4][64];    // partials [parity][wave][lane], dbl-buffered,
                                      // conflict-free both directions (R5)
    __shared__ int   sTok[LL];
    __shared__ int   sK[LL];          // emitted symbols; flushed to global at end

    const int tid = threadIdx.x;
    const int w   = tid >> 6;
    const int l   = tid & 63;
    const int b   = blockIdx.x;

    for (int i = tid; i < V * HH; i += 256) sW1[i] = W1[i];
    for (int i = tid; i < LL; i += 256) sTok[i] = xtok[(size_t)b * LL + i];

    // Lane roles: lanes 0..22 own net[:V] (loc), lanes 32..54 own net[V:] (scale).
    const bool activeA = (l < V);
    const bool activeB = (l >= 32 && l < 32 + V);
    const bool active  = activeA || activeB;
    const int  col     = activeA ? l : (activeB ? (l - 32 + V) : 0);

    // h_pre in double: 1024 sequential adds stay within 1 ulp of exact c@W1+b1.
    double h_pre = (double)b1[tid];

    const float bias = active ? b2[col] : 0.f;

    // W2 chunk as 32 float2 pairs: lane holds W2[64w+ii][col], PINNED in VGPR
    // pairs so v_pk_fma_f32 consumes them directly (R7: pk_fma halves matvec
    // issue, -77us). asm "+v" per R4: stops in-loop rematerialization.
    f32x2 wreg2[32];
    #pragma unroll
    for (int ii = 0; ii < 32; ++ii) {
        wreg2[ii].x = active ? W2[(size_t)(64 * w + 2 * ii + 0) * NOUT + col] : 0.f;
        wreg2[ii].y = active ? W2[(size_t)(64 * w + 2 * ii + 1) * NOUT + col] : 0.f;
    }
    #pragma unroll
    for (int ii = 0; ii < 32; ++ii) asm volatile("" : "+v"(wreg2[ii]));

    __syncthreads();

    // peeled first sV publish (was at loop top in R7; bit-identical sequence)
    sV[tid] = fmaxf((float)h_pre, 0.f);

    for (int t = 0; t < LL; ++t) {
        // token: uniform; read early (latency hidden under matvec); SALU tail.
        const int tok = __builtin_amdgcn_readfirstlane(sTok[t]);

        // matvec partial at prio 0 (issue-elastic): wave w covers rows
        // [64w,64w+64) of sV written by ITSELF last iteration (in-order DS).
        // Uniform-address b128 reads broadcast; pk(a0+=vx*w0, a1+=vy*w1) is
        // bit-identical to the two scalar fmafs -> (a0+a1)+(a2+a3) preserved.
        const f32x4* pv = (const f32x4*)(sV + 64 * w);
        f32x2 A01 = {0.f, 0.f};
        f32x2 A23 = {0.f, 0.f};
        #pragma unroll
        for (int q = 0; q < 16; ++q) {
            f32x4 vv = pv[q];
            f32x2 vlo = __builtin_shufflevector(vv, vv, 0, 1);
            f32x2 vhi = __builtin_shufflevector(vv, vv, 2, 3);
            asm("v_pk_fma_f32 %0, %1, %2, %0" : "+v"(A01) : "v"(vlo), "v"(wreg2[2 * q + 0]));
            asm("v_pk_fma_f32 %0, %1, %2, %0" : "+v"(A23) : "v"(vhi), "v"(wreg2[2 * q + 1]));
        }
        const int p = t & 1;
        sP[p][w][l] = (A01.x + A01.y) + (A23.x + A23.y);   // conflict-free b32 write
        __syncthreads();   // the ONLY barrier per step

        // ---- serial chain: prio 1 so the co-resident block's matvec bursts
        // don't delay chain-critical ops ----
        __builtin_amdgcn_s_setprio(1);

        // reduce 4 wave-partials + bias; stride-64 scalar reads pair into
        // ds_read2_b32, conflict-free. Sum order (s0+s1)+(s2+s3) preserved.
        const float* pp = &sP[p][0][l];
        const float p0 = pp[0], p1 = pp[64], p2 = pp[128], p3 = pp[192];
        float net = bias + ((p0 + p1) + (p2 + p3));
        int ib = __float_as_int(net);
        unsigned monoraw = (ib < 0) ? ~(unsigned)ib : ((unsigned)ib ^ 0x80000000u);
        const unsigned orig = active ? monoraw : 0u;  // lane's OWN key, preserved

        // dual 32-lane-half max-reduce on a separate register (VALU DPP only)
        unsigned red = orig;
        DPPMAX(red, 0xB1,  0xF);  // quad_perm xor1
        DPPMAX(red, 0x4E,  0xF);  // quad_perm xor2
        DPPMAX(red, 0x141, 0xF);  // row_half_mirror (combine 4-groups)
        DPPMAX(red, 0x140, 0xF);  // row_mirror      (combine 8-groups)
        DPPMAX(red, 0x142, 0xA);  // row_bcast15 into rows 1,3 (combine rows)
        const unsigned sA = (unsigned)__builtin_amdgcn_readlane((int)red, 16);
        const unsigned sB = (unsigned)__builtin_amdgcn_readlane((int)red, 48);

        // winner = lowest lane whose ORIGINAL key equals its half's max
        // (lowest lane == lowest index == np first-max tie-break)
        const unsigned cmpv = (l < 32) ? sA : sB;
        const unsigned long long bal = __ballot(orig == cmpv);
        const int loc = __builtin_ctzll(bal & 0xFFFFFFFFull);  // lane == col
        const int sc  = __builtin_ctzll(bal >> 32);

        // inverse mod 23 from packed scalar table (pure SALU; tok is SGPR)
        const unsigned long long tt = (sc < 12) ? INV_T0 : INV_T1;
        const int sh  = 5 * (sc - ((sc >= 12) ? 12 : 0));
        const int inv = (int)((tt >> sh) & 31);

        int m = tok - loc;
        m += (m >> 31) & V;            // (tok - loc) mod 23
        const int k = (m * inv) % V;   // compiler magic-mul for %23

        // h update + next step's relu/publish, still at prio 1 (chain tail)
        h_pre += (double)sW1[k * HH + tid];   // stride-1, conflict-free
        sV[tid] = fmaxf((float)h_pre, 0.f);   // for iteration t+1 (own window)

        if (tid == 0) sK[t] = k;
        __builtin_amdgcn_s_setprio(0);
    }

    __syncthreads();
    float* outb = out + (size_t)b * LL * V;
    for (int t = tid; t < LL; t += 256)
        outb[t * V + sK[t]] = 1.0f;
}

extern "C" void kernel_launch(void* const* d_in, const int* in_sizes, int n_in,
                              void* d_out, int out_size, void* d_ws, size_t ws_size,
                              hipStream_t stream) {
    const int*   xtok = (const int*)d_in[0];
    const float* W1   = (const float*)d_in[1];
    const float* b1   = (const float*)d_in[2];
    const float* W2   = (const float*)d_in[3];
    const float* b2   = (const float*)d_in[4];
    float* out = (float*)d_out;

    // d_out poisoned 0xAA pre-launch: zero it, kernel scatters the 1.0s
    hipMemsetAsync(out, 0, (size_t)out_size * sizeof(float), stream);
    daf_kernel<<<BB, 256, 0, stream>>>(xtok, W1, b1, W2, b2, out);
}